// Round 14
// baseline (4689.354 us; speedup 1.0000x reference)
//
#include <hip/hip_runtime.h>

// AdaptiveDownsampling: farthest point sampling (B=8, N=8192, m=4096) + gather.
// Outputs concatenated flat: dp [8,4096,3] then df [8,4096,256], float32.
//
// r2: np reference computes in float64 -> exact path must be fp64.
// r6: fp32 screen + rare exact fp64 path. 5275 us.
// r7: DPP wave max, packed-fp32 screen, precomputed margin. 4239 us.
// r8: FAILED (5264): redundant block reduce in every wave.
// r9: dirty-wave caching + fused v_max_u32_dpp ladders. 4198 us.
// r10: FAILED (5165): Morton sort + sphere cull on the pacing path.
// r11: FAILED (6141): payload atomics w/ VGPR-cached coords -> spill.
// r12/r13: FAILED (5532/5518): bundled changes; spill; waves_per_eu inert.
// r14: r9 + ballot/readlane replacing DPP ladders 2+3. 3925 us (BEST).
//     Clean: FETCH 425 / WRITE 512 / VGPR 64 / VALU 1.60%. Ballot exonerated;
//     r12's poison was its screen/publish restructure.
// r15: kill the post-barrier-B chained double LDS RT (widx read -> s_pts
//     read, ~120cy dependent) with VGPR-NEUTRAL payload publish:
//     - reduce caches SGPRs only: wn (min idx at wave max), wL (lane holding
//       it), wj (slot 0..7). No new VGPR liveness (r11's mistake).
//     - owner wave (mybits==bmaxbits), between A and B: coords via
//       readlane(pxp[wj], wL) from always-live coord regs; lane0 publishes
//       3x atomicMin(s_pay[c], (wn<<32)|coord_bits). wn unique per point ->
//       wn-major ordering is the exact numpy tie-break; coord bits never
//       decide. Bit-identical coords to the old s_pts reads.
//     - post-B: ONE parallel RT reads idx+coords. s_pts (96KB LDS + staging
//       + dependent RT) deleted.
//     (Resubmit: GPU acquisition timeout.)

typedef float v2f __attribute__((ext_vector_type(2)));

#define BATCH 8
#define NPTS  8192
#define MSEL  4096
#define NFEAT 256
#define BLOCK 1024

// fp64 square, opaque to the compiler so no v_fma_f64 contraction can merge
// the following adds (numpy float64 does separate mul / add / add).
__device__ __forceinline__ double sqd(double x) {
    double r;
    asm("v_mul_f64 %0, %1, %1" : "=v"(r) : "v"(x));
    return r;
}

// Exact 64-lane u32 max via fused DPP max ops, result wave-uniform in SGPR.
// bound_ctrl:0 => out-of-range DPP sources read 0 (identity for unsigned max).
// Requires full exec / uniform control flow at the call site.
__device__ __forceinline__ unsigned wave_umax_rl(unsigned v) {
    unsigned s;
    asm volatile(
        "s_nop 1\n\t"
        "v_max_u32_dpp %1, %1, %1 row_shr:1  row_mask:0xf bank_mask:0xf bound_ctrl:0\n\t"
        "s_nop 1\n\t"
        "v_max_u32_dpp %1, %1, %1 row_shr:2  row_mask:0xf bank_mask:0xf bound_ctrl:0\n\t"
        "s_nop 1\n\t"
        "v_max_u32_dpp %1, %1, %1 row_shr:4  row_mask:0xf bank_mask:0xf bound_ctrl:0\n\t"
        "s_nop 1\n\t"
        "v_max_u32_dpp %1, %1, %1 row_shr:8  row_mask:0xf bank_mask:0xf bound_ctrl:0\n\t"
        "s_nop 1\n\t"
        "v_max_u32_dpp %1, %1, %1 row_bcast:15 row_mask:0xf bank_mask:0xf bound_ctrl:0\n\t"
        "s_nop 1\n\t"
        "v_max_u32_dpp %1, %1, %1 row_bcast:31 row_mask:0xf bank_mask:0xf bound_ctrl:0\n\t"
        "s_nop 1\n\t"
        "v_readlane_b32 %0, %1, 63"
        : "=s"(s), "+v"(v));
    return s;
}

__launch_bounds__(BLOCK, 1)
__global__ void fps_kernel(const float* __restrict__ pts,   // [B, N, 3]
                           float* __restrict__ dp,          // [B, M, 3]
                           int* __restrict__ idx_out)       // [B, M]
{
    __shared__ unsigned long long s_bmax[2];      // block max, double bits (nonneg)
    __shared__ unsigned long long s_pay[2][3];    // (wn<<32)|coord_bits, atomicMin

    const int b    = blockIdx.x;
    const int tid  = threadIdx.x;
    const int lane = tid & 63;
    const float* p = pts + (size_t)b * NPTS * 3;

    if (tid == 0) {
        s_bmax[0] = 0ull;    s_bmax[1] = 0ull;
        s_pay[0][0] = ~0ull; s_pay[0][1] = ~0ull; s_pay[0][2] = ~0ull;
        s_pay[1][0] = ~0ull; s_pay[1][1] = ~0ull; s_pay[1][2] = ~0ull;
    }

    // Coords as float2 pairs (slots 2P, 2P+1) -> packed-fp32 screen.
    // mind (fp64 exact) + mfm (pre-margined fp32 screen threshold) per slot.
#define DECLP(P, J0, J1) \
    v2f pxp##P = { p[(tid + J0 * 1024) * 3 + 0], p[(tid + J1 * 1024) * 3 + 0] }; \
    v2f pyp##P = { p[(tid + J0 * 1024) * 3 + 1], p[(tid + J1 * 1024) * 3 + 1] }; \
    v2f pzp##P = { p[(tid + J0 * 1024) * 3 + 2], p[(tid + J1 * 1024) * 3 + 2] };
    DECLP(0, 0, 1) DECLP(1, 2, 3) DECLP(2, 4, 5) DECLP(3, 6, 7)
#undef DECLP
    double mind0 = 1e10, mind1 = 1e10, mind2 = 1e10, mind3 = 1e10;
    double mind4 = 1e10, mind5 = 1e10, mind6 = 1e10, mind7 = 1e10;
    float  mfm0 = 1.0001e10f, mfm1 = 1.0001e10f, mfm2 = 1.0001e10f, mfm3 = 1.0001e10f;
    float  mfm4 = 1.0001e10f, mfm5 = 1.0001e10f, mfm6 = 1.0001e10f, mfm7 = 1.0001e10f;

    // Selection 0 is point 0 (deterministic start).
    float cx = p[0], cy = p[1], cz = p[2];
    if (tid == 0) {
        dp[(size_t)b * MSEL * 3 + 0] = cx;
        dp[(size_t)b * MSEL * 3 + 1] = cy;
        dp[(size_t)b * MSEL * 3 + 2] = cz;
        idx_out[b * MSEL + 0] = 0;
    }

    const int wavebase = __builtin_amdgcn_readfirstlane((int)tid);  // lane0's tid

    double   tbv   = 0.0;          // cached thread-local max of mind0..7
    bool     dirty = true;         // lane updated since last wave reduce
    unsigned whi = 0u, wlo = 0u;   // cached wave max (double bits), SGPR
    unsigned wn  = 0x7fffffffu;    // cached wave min-index-at-max, SGPR
    int      wL  = 0;              // cached lane holding wn, SGPR
    int      wj  = 0;              // cached slot (0..7) of wn, SGPR

    __syncthreads();   // slot inits visible

    for (int k = 1; k < MSEL; ++k) {
        const v2f cx2 = {cx, cx}, cy2 = {cy, cy}, cz2 = {cz, cz};

        // --- packed fp32 screen; exact fp64 update only on trigger (r9) ---
#define EX64(PX, PY, PZ, J) { \
        const double ddx = (double)(PX) - (double)cx; \
        const double ddy = (double)(PY) - (double)cy; \
        const double ddz = (double)(PZ) - (double)cz; \
        const double dd  = (sqd(ddx) + sqd(ddy)) + sqd(ddz); \
        if (dd < mind##J) { mind##J = dd; mfm##J = (float)dd * 1.0001f; dirty = true; } }
#define UPDP(P, J0, J1) { \
        const v2f dx = pxp##P - cx2, dy = pyp##P - cy2, dz = pzp##P - cz2; \
        const v2f d  = dx * dx + dy * dy + dz * dz; \
        if (d.x < mfm##J0) EX64(pxp##P.x, pyp##P.x, pzp##P.x, J0) \
        if (d.y < mfm##J1) EX64(pxp##P.y, pyp##P.y, pzp##P.y, J1) }
        UPDP(0, 0, 1) UPDP(1, 2, 3) UPDP(2, 4, 5) UPDP(3, 6, 7)
#undef UPDP
#undef EX64

        // --- wave reduce only if some lane in this wave updated ---
        if (__any(dirty)) {
            const double a0 = fmax(mind0, mind1), a1 = fmax(mind2, mind3);
            const double a2 = fmax(mind4, mind5), a3 = fmax(mind6, mind7);
            tbv = fmax(fmax(a0, a1), fmax(a2, a3));
            dirty = false;

            const unsigned long long tb = (unsigned long long)__double_as_longlong(tbv);
            const unsigned thi = (unsigned)(tb >> 32);
            const unsigned tlo = (unsigned)tb;
            whi = wave_umax_rl(thi);

            // per-lane min global idx among THIS lane's slots at its own max
            // (branch-free cndmask chain; numpy tie-break: scan high slot ->
            // low so the smallest index wins last assignment).
            unsigned n = 0x7fffffffu;
            if (mind7 == tbv) n = tid + 7 * 1024;
            if (mind6 == tbv) n = tid + 6 * 1024;
            if (mind5 == tbv) n = tid + 5 * 1024;
            if (mind4 == tbv) n = tid + 4 * 1024;
            if (mind3 == tbv) n = tid + 3 * 1024;
            if (mind2 == tbv) n = tid + 2 * 1024;
            if (mind1 == tbv) n = tid + 1 * 1024;
            if (mind0 == tbv) n = tid;

            // Single lane holds the hi-32 max (typical): that lane owns the
            // full wave max -> 2 readlanes replace ladder2 + ladder3 + gate.
            const unsigned long long hiown = __ballot(thi == whi);
            if (__popcll(hiown) == 1) {
                wL  = (int)(__ffsll(hiown) - 1);
                wlo = (unsigned)__builtin_amdgcn_readlane((int)tlo, wL);
                wn  = (unsigned)__builtin_amdgcn_readlane((int)n,   wL);
            } else {            // exact fallback on multi-lane hi ties
                wlo = wave_umax_rl(thi == whi ? tlo : 0u);
                const unsigned ng = (thi == whi && tlo == wlo) ? n : 0x7fffffffu;
                wn = ~wave_umax_rl(~ng);   // min over owner lanes
                wL = (int)(__ffsll(__ballot(thi == whi && tlo == wlo && n == wn)) - 1);
            }
            wj = (int)((wn - (unsigned)(wavebase + wL)) >> 10);   // slot 0..7
        }

        const unsigned long long mybits =
            ((unsigned long long)whi << 32) | (unsigned long long)wlo;
        const int buf = k & 1;
        if (lane == 0) atomicMax(&s_bmax[buf], mybits);
        __syncthreads();                                   // barrier A

        const unsigned long long bmaxbits = s_bmax[buf];
        if (tid == 0) {   // reset NEXT iter's slots (between barriers A and B)
            s_bmax[buf ^ 1] = 0ull;
            s_pay[buf ^ 1][0] = ~0ull;
            s_pay[buf ^ 1][1] = ~0ull;
            s_pay[buf ^ 1][2] = ~0ull;
        }

        // --- owner wave(s): extract winner coords from live regs via
        //     readlane(pxp[wj], wL); lane0 publishes (wn<<32)|coord.
        //     wn unique per point -> wn-major atomicMin = exact tie-break. ---
        if (mybits == bmaxbits) {
            unsigned oxb, oyb, ozb;
#define RL(V) ((unsigned)__builtin_amdgcn_readlane((int)__float_as_uint(V), wL))
            switch (wj) {
              case 0: oxb = RL(pxp0.x); oyb = RL(pyp0.x); ozb = RL(pzp0.x); break;
              case 1: oxb = RL(pxp0.y); oyb = RL(pyp0.y); ozb = RL(pzp0.y); break;
              case 2: oxb = RL(pxp1.x); oyb = RL(pyp1.x); ozb = RL(pzp1.x); break;
              case 3: oxb = RL(pxp1.y); oyb = RL(pyp1.y); ozb = RL(pzp1.y); break;
              case 4: oxb = RL(pxp2.x); oyb = RL(pyp2.x); ozb = RL(pzp2.x); break;
              case 5: oxb = RL(pxp2.y); oyb = RL(pyp2.y); ozb = RL(pzp2.y); break;
              case 6: oxb = RL(pxp3.x); oyb = RL(pyp3.x); ozb = RL(pzp3.x); break;
              default: oxb = RL(pxp3.y); oyb = RL(pyp3.y); ozb = RL(pzp3.y); break;
            }
#undef RL
            if (lane == 0) {
                const unsigned long long h = (unsigned long long)wn << 32;
                atomicMin(&s_pay[buf][0], h | (unsigned long long)oxb);
                atomicMin(&s_pay[buf][1], h | (unsigned long long)oyb);
                atomicMin(&s_pay[buf][2], h | (unsigned long long)ozb);
            }
        }
        __syncthreads();                                   // barrier B

        // --- single parallel LDS round-trip: idx + coords from payloads ---
        const unsigned long long p0 = s_pay[buf][0];
        const unsigned long long p1 = s_pay[buf][1];
        const unsigned long long p2 = s_pay[buf][2];
        const int widx = (int)(p0 >> 32);
        cx = __uint_as_float((unsigned)p0);
        cy = __uint_as_float((unsigned)p1);
        cz = __uint_as_float((unsigned)p2);
        if (tid == 0) {
            idx_out[b * MSEL + k] = widx;
            float* o = dp + ((size_t)b * MSEL + k) * 3;
            o[0] = cx; o[1] = cy; o[2] = cz;
        }
    }
}

// One wave per selected row; lane i moves one float4 (64 * 16B = 1024B = full row).
__global__ void gather_kernel(const float* __restrict__ feats,  // [B, N, C]
                              const int* __restrict__ idx,      // [B, M]
                              float* __restrict__ df)           // [B, M, C]
{
    const int row  = blockIdx.x * 4 + (threadIdx.x >> 6);  // [0, B*M)
    const int lane = threadIdx.x & 63;
    const int b    = row >> 12;         // MSEL = 4096 rows per batch
    const int src  = idx[row];
    const float4* s = (const float4*)(feats + ((size_t)b * NPTS + src) * NFEAT);
    float4*       d = (float4*)(df + (size_t)row * NFEAT);
    d[lane] = s[lane];
}

extern "C" void kernel_launch(void* const* d_in, const int* in_sizes, int n_in,
                              void* d_out, int out_size, void* d_ws, size_t ws_size,
                              hipStream_t stream)
{
    const float* points   = (const float*)d_in[0];   // [8, 8192, 3]
    const float* features = (const float*)d_in[1];   // [8, 8192, 256]
    float* out = (float*)d_out;
    float* dp  = out;                                // [8, 4096, 3]
    float* df  = out + (size_t)BATCH * MSEL * 3;     // [8, 4096, 256]
    int*   idx_ws = (int*)d_ws;                      // [8, 4096] = 128 KB scratch

    fps_kernel<<<BATCH, BLOCK, 0, stream>>>(points, dp, idx_ws);
    gather_kernel<<<(BATCH * MSEL) / 4, 256, 0, stream>>>(features, idx_ws, df);
}

// Round 15
// 3982.709 us; speedup vs baseline: 1.1774x; 1.1774x over previous
//
#include <hip/hip_runtime.h>

// AdaptiveDownsampling: farthest point sampling (B=8, N=8192, m=4096) + gather.
// Outputs concatenated flat: dp [8,4096,3] then df [8,4096,256], float32.
//
// r2: np reference computes in float64 -> exact path must be fp64.
// r6: fp32 screen + rare exact fp64 path. 5275 us.
// r7: DPP wave max, packed-fp32 screen, precomputed margin. 4239 us.
// r8: FAILED (5264): single barrier + redundant block reduce, but with THREE
//     full DPP ladders per wave per iter (~250cy) -> VALU tax swamped gains.
// r9: dirty-wave caching + fused ladders. 4198 us.
// r10: FAILED (5165): cull test added serial work to the pacing path.
// r11: FAILED (6141): payload atomics w/ VGPR-cached coords -> spill.
// r12/r13: FAILED (5532/5518): bundled changes; spill; waves_per_eu inert.
// r14: r9 + ballot/readlane replacing DPP ladders 2+3. 3925 us (BEST).
//     Clean: FETCH 425 / WRITE 512 / VGPR 64 / VALU 1.60%.
// r15: FAILED (4689): payload publish moved ~200cy INTO the A->B barrier
//     window (readlane switch + 3 u64 atomicMin + drain). Lesson: work
//     between barriers costs full price; post-B latency partially overlaps
//     across waves. Reverted.
// r16: ONE barrier, ZERO atomics. Every wave's lane0 writes cached
//     (whi,wlo,wn) uint4 to its OWN slot (plain ds_write, unconditional so
//     double-buffered slots are never stale); one __syncthreads; every wave
//     reads 16 slots (lane&15 -> broadcast, conflict-free) and block-reduces
//     with ONE hi-ladder + ballot/readlane shortcut (~70cy; r8's poison was
//     3 ladders ~250cy). bn wave-uniform -> coords via one s_pts RT.
//     Deletes per iter: 1 barrier, atomicMax+drain, atomicMin+drain, 1 RT.
//     Race-free via 2-parity argument: passing barrier k+1 implies parity-p
//     reads of iter k are done before parity-p rewrite at iter k+2.

typedef float v2f __attribute__((ext_vector_type(2)));

#define BATCH 8
#define NPTS  8192
#define MSEL  4096
#define NFEAT 256
#define BLOCK 1024
#define NWAVE (BLOCK / 64)

// fp64 square, opaque to the compiler so no v_fma_f64 contraction can merge
// the following adds (numpy float64 does separate mul / add / add).
__device__ __forceinline__ double sqd(double x) {
    double r;
    asm("v_mul_f64 %0, %1, %1" : "=v"(r) : "v"(x));
    return r;
}

// Exact 64-lane u32 max via fused DPP max ops, result wave-uniform in SGPR.
// bound_ctrl:0 => out-of-range DPP sources read 0 (identity for unsigned max).
// Requires full exec / uniform control flow at the call site.
__device__ __forceinline__ unsigned wave_umax_rl(unsigned v) {
    unsigned s;
    asm volatile(
        "s_nop 1\n\t"
        "v_max_u32_dpp %1, %1, %1 row_shr:1  row_mask:0xf bank_mask:0xf bound_ctrl:0\n\t"
        "s_nop 1\n\t"
        "v_max_u32_dpp %1, %1, %1 row_shr:2  row_mask:0xf bank_mask:0xf bound_ctrl:0\n\t"
        "s_nop 1\n\t"
        "v_max_u32_dpp %1, %1, %1 row_shr:4  row_mask:0xf bank_mask:0xf bound_ctrl:0\n\t"
        "s_nop 1\n\t"
        "v_max_u32_dpp %1, %1, %1 row_shr:8  row_mask:0xf bank_mask:0xf bound_ctrl:0\n\t"
        "s_nop 1\n\t"
        "v_max_u32_dpp %1, %1, %1 row_bcast:15 row_mask:0xf bank_mask:0xf bound_ctrl:0\n\t"
        "s_nop 1\n\t"
        "v_max_u32_dpp %1, %1, %1 row_bcast:31 row_mask:0xf bank_mask:0xf bound_ctrl:0\n\t"
        "s_nop 1\n\t"
        "v_readlane_b32 %0, %1, 63"
        : "=s"(s), "+v"(v));
    return s;
}

__launch_bounds__(BLOCK, 1)
__global__ void fps_kernel(const float* __restrict__ pts,   // [B, N, 3]
                           float* __restrict__ dp,          // [B, M, 3]
                           int* __restrict__ idx_out)       // [B, M]
{
    __shared__ float s_pts[NPTS * 3];      // 96 KB fp32 copy (winner broadcast)
    __shared__ uint4 s_slot[2][NWAVE];     // per-wave (whi, wlo, wn, 0)

    const int b    = blockIdx.x;
    const int tid  = threadIdx.x;
    const int lane = tid & 63;
    const int wid  = tid >> 6;
    const float* p = pts + (size_t)b * NPTS * 3;

    for (int i = tid; i < NPTS * 3; i += BLOCK) s_pts[i] = p[i];

    // Coords as float2 pairs (slots 2P, 2P+1) -> packed-fp32 screen.
    // mind (fp64 exact) + mfm (pre-margined fp32 screen threshold) per slot.
#define DECLP(P, J0, J1) \
    v2f pxp##P = { p[(tid + J0 * 1024) * 3 + 0], p[(tid + J1 * 1024) * 3 + 0] }; \
    v2f pyp##P = { p[(tid + J0 * 1024) * 3 + 1], p[(tid + J1 * 1024) * 3 + 1] }; \
    v2f pzp##P = { p[(tid + J0 * 1024) * 3 + 2], p[(tid + J1 * 1024) * 3 + 2] };
    DECLP(0, 0, 1) DECLP(1, 2, 3) DECLP(2, 4, 5) DECLP(3, 6, 7)
#undef DECLP
    double mind0 = 1e10, mind1 = 1e10, mind2 = 1e10, mind3 = 1e10;
    double mind4 = 1e10, mind5 = 1e10, mind6 = 1e10, mind7 = 1e10;
    float  mfm0 = 1.0001e10f, mfm1 = 1.0001e10f, mfm2 = 1.0001e10f, mfm3 = 1.0001e10f;
    float  mfm4 = 1.0001e10f, mfm5 = 1.0001e10f, mfm6 = 1.0001e10f, mfm7 = 1.0001e10f;

    // Selection 0 is point 0 (deterministic start).
    float cx = p[0], cy = p[1], cz = p[2];
    if (tid == 0) {
        dp[(size_t)b * MSEL * 3 + 0] = cx;
        dp[(size_t)b * MSEL * 3 + 1] = cy;
        dp[(size_t)b * MSEL * 3 + 2] = cz;
        idx_out[b * MSEL + 0] = 0;
    }

    double   tbv   = 0.0;          // cached thread-local max of mind0..7
    bool     dirty = true;         // lane updated since last wave reduce
    unsigned whi = 0u, wlo = 0u;   // cached wave max (double bits), SGPR
    unsigned wn  = 0x7fffffffu;    // cached wave min-index-at-max, SGPR

    __syncthreads();   // s_pts visible

    for (int k = 1; k < MSEL; ++k) {
        const v2f cx2 = {cx, cx}, cy2 = {cy, cy}, cz2 = {cz, cz};

        // --- packed fp32 screen; exact fp64 update only on trigger (r9) ---
#define EX64(PX, PY, PZ, J) { \
        const double ddx = (double)(PX) - (double)cx; \
        const double ddy = (double)(PY) - (double)cy; \
        const double ddz = (double)(PZ) - (double)cz; \
        const double dd  = (sqd(ddx) + sqd(ddy)) + sqd(ddz); \
        if (dd < mind##J) { mind##J = dd; mfm##J = (float)dd * 1.0001f; dirty = true; } }
#define UPDP(P, J0, J1) { \
        const v2f dx = pxp##P - cx2, dy = pyp##P - cy2, dz = pzp##P - cz2; \
        const v2f d  = dx * dx + dy * dy + dz * dz; \
        if (d.x < mfm##J0) EX64(pxp##P.x, pyp##P.x, pzp##P.x, J0) \
        if (d.y < mfm##J1) EX64(pxp##P.y, pyp##P.y, pzp##P.y, J1) }
        UPDP(0, 0, 1) UPDP(1, 2, 3) UPDP(2, 4, 5) UPDP(3, 6, 7)
#undef UPDP
#undef EX64

        // --- wave reduce only if some lane in this wave updated (r14) ---
        if (__any(dirty)) {
            const double a0 = fmax(mind0, mind1), a1 = fmax(mind2, mind3);
            const double a2 = fmax(mind4, mind5), a3 = fmax(mind6, mind7);
            tbv = fmax(fmax(a0, a1), fmax(a2, a3));
            dirty = false;

            const unsigned long long tb = (unsigned long long)__double_as_longlong(tbv);
            const unsigned thi = (unsigned)(tb >> 32);
            const unsigned tlo = (unsigned)tb;
            whi = wave_umax_rl(thi);

            // per-lane min global idx among THIS lane's slots at its own max
            // (branch-free cndmask chain; numpy tie-break: scan high slot ->
            // low so the smallest index wins last assignment).
            unsigned n = 0x7fffffffu;
            if (mind7 == tbv) n = tid + 7 * 1024;
            if (mind6 == tbv) n = tid + 6 * 1024;
            if (mind5 == tbv) n = tid + 5 * 1024;
            if (mind4 == tbv) n = tid + 4 * 1024;
            if (mind3 == tbv) n = tid + 3 * 1024;
            if (mind2 == tbv) n = tid + 2 * 1024;
            if (mind1 == tbv) n = tid + 1 * 1024;
            if (mind0 == tbv) n = tid;

            // Single lane holds the hi-32 max (typical): that lane owns the
            // full wave max -> 2 readlanes replace ladder2 + ladder3 + gate.
            const unsigned long long hiown = __ballot(thi == whi);
            if (__popcll(hiown) == 1) {
                const int L = (int)(__ffsll(hiown) - 1);
                wlo = (unsigned)__builtin_amdgcn_readlane((int)tlo, L);
                wn  = (unsigned)__builtin_amdgcn_readlane((int)n,   L);
            } else {            // exact fallback on multi-lane hi ties
                wlo = wave_umax_rl(thi == whi ? tlo : 0u);
                const unsigned ng = (thi == whi && tlo == wlo) ? n : 0x7fffffffu;
                wn = ~wave_umax_rl(~ng);   // min over owner lanes
            }
        }

        // --- publish cached wave result to own slot; ONE barrier ---
        const int buf = k & 1;
        if (lane == 0) s_slot[buf][wid] = make_uint4(whi, wlo, wn, 0u);
        __syncthreads();

        // --- block reduce over 16 slots in every wave (entries duplicated
        //     4x across lane groups; lanes 0-15 cover each entry once) ---
        const uint4 ent = s_slot[buf][lane & (NWAVE - 1)];
        const unsigned bhi = wave_umax_rl(ent.x);
        unsigned blo, bn;
        const unsigned own16 = (unsigned)__ballot(ent.x == bhi) & 0xFFFFu;
        if (__popc(own16) == 1) {   // unique hi-winner entry (typical)
            const int L = __ffs(own16) - 1;
            blo = (unsigned)__builtin_amdgcn_readlane((int)ent.y, L);
            bn  = (unsigned)__builtin_amdgcn_readlane((int)ent.z, L);
        } else {                    // exact fallback on hi ties across waves
            blo = wave_umax_rl(ent.x == bhi ? ent.y : 0u);
            const unsigned ng = (ent.x == bhi && ent.y == blo) ? ent.z : 0xffffffffu;
            bn = ~wave_umax_rl(~ng);   // min idx among full-match entries
        }

        // --- winner coords from LDS (wave-uniform addr = broadcast) ---
        const int widx = (int)bn;
        const float wx = s_pts[widx * 3 + 0];
        const float wy = s_pts[widx * 3 + 1];
        const float wz = s_pts[widx * 3 + 2];
        if (tid == 0) {
            idx_out[b * MSEL + k] = widx;
            float* o = dp + ((size_t)b * MSEL + k) * 3;
            o[0] = wx; o[1] = wy; o[2] = wz;
        }
        cx = wx; cy = wy; cz = wz;
    }
}

// One wave per selected row; lane i moves one float4 (64 * 16B = 1024B = full row).
__global__ void gather_kernel(const float* __restrict__ feats,  // [B, N, C]
                              const int* __restrict__ idx,      // [B, M]
                              float* __restrict__ df)           // [B, M, C]
{
    const int row  = blockIdx.x * 4 + (threadIdx.x >> 6);  // [0, B*M)
    const int lane = threadIdx.x & 63;
    const int b    = row >> 12;         // MSEL = 4096 rows per batch
    const int src  = idx[row];
    const float4* s = (const float4*)(feats + ((size_t)b * NPTS + src) * NFEAT);
    float4*       d = (float4*)(df + (size_t)row * NFEAT);
    d[lane] = s[lane];
}

extern "C" void kernel_launch(void* const* d_in, const int* in_sizes, int n_in,
                              void* d_out, int out_size, void* d_ws, size_t ws_size,
                              hipStream_t stream)
{
    const float* points   = (const float*)d_in[0];   // [8, 8192, 3]
    const float* features = (const float*)d_in[1];   // [8, 8192, 256]
    float* out = (float*)d_out;
    float* dp  = out;                                // [8, 4096, 3]
    float* df  = out + (size_t)BATCH * MSEL * 3;     // [8, 4096, 256]
    int*   idx_ws = (int*)d_ws;                      // [8, 4096] = 128 KB scratch

    fps_kernel<<<BATCH, BLOCK, 0, stream>>>(points, dp, idx_ws);
    gather_kernel<<<(BATCH * MSEL) / 4, 256, 0, stream>>>(features, idx_ws, df);
}